// Round 1
// baseline (335.466 us; speedup 1.0000x reference)
//
#include <hip/hip_runtime.h>

typedef unsigned short u16;
typedef unsigned int u32;
typedef __attribute__((ext_vector_type(8))) __bf16 bf16x8;
typedef __attribute__((ext_vector_type(8))) _Float16 f16x8;
typedef __attribute__((ext_vector_type(4))) float f32x4;

// ---------- helpers ----------
__device__ __forceinline__ float b2f(u16 b) {
    union { u32 u; float f; } v; v.u = ((u32)b) << 16; return v.f;
}
__device__ __forceinline__ u16 f2bf(float f) {
    union { float f; u32 u; } v; v.f = f;
    u32 u = v.u;
    return (u16)((u + 0x7fffu + ((u >> 16) & 1u)) >> 16);  // RNE
}
__device__ __forceinline__ u16 f2h(float f) {
    _Float16 h = (_Float16)f;
    return __builtin_bit_cast(u16, h);
}
// native RNE cvt pair -> packed u32 (compiler emits v_cvt_pk_bf16_f32)
__device__ __forceinline__ u32 pkbf2(float a, float b) {
    u16 x = __builtin_bit_cast(u16, (__bf16)a);
    u16 y = __builtin_bit_cast(u16, (__bf16)b);
    return (u32)x | ((u32)y << 16);
}
__device__ __forceinline__ bf16x8 ldg8b(const u16* p) {
    uint4 v = *(const uint4*)p;
    return __builtin_bit_cast(bf16x8, v);
}
__device__ __forceinline__ f16x8 ldg8h(const u16* p) {
    uint4 v = *(const uint4*)p;
    return __builtin_bit_cast(f16x8, v);
}
__device__ __forceinline__ f32x4 mfma_bf(bf16x8 a, bf16x8 b, f32x4 c) {
    return __builtin_amdgcn_mfma_f32_16x16x32_bf16(a, b, c, 0, 0, 0);
}
__device__ __forceinline__ f32x4 mfma_h(f16x8 a, f16x8 b, f32x4 c) {
    return __builtin_amdgcn_mfma_f32_16x16x32_f16(a, b, c, 0, 0, 0);
}

#define LOG2E 1.44269504088896340736f

// Q global layout: per batch, row p (4096): 64 fp16, elem slot = d ^ ((p&7)*8)
// Gt global layout: per (n, step s of 64 p): 16384 elems: ch*64 + ((pp&~7)^((ch&7)*8)) + (pp&7)

// ---------- K0: hi/lo bf16 split of W, transposed: Wt[d][c] ----------
__global__ void k0_wt(const float* __restrict__ Wq,
                      u16* __restrict__ Wthi, u16* __restrict__ Wtlo) {
    int idx = blockIdx.x * 256 + threadIdx.x;   // 64 blocks -> 16384
    int c = idx >> 6, d = idx & 63;
    float w = Wq[idx];
    u16 hi = f2bf(w);
    float rem = w - b2f(hi);
    Wthi[d * 256 + c] = hi;
    Wtlo[d * 256 + c] = f2bf(rem);
}

// ---------- K1: Q = F*W (hi/lo split MFMA), fp16 out, XOR-swizzled rows ----------
__global__ __launch_bounds__(256) void k1_query(
    const float* __restrict__ F, const u16* __restrict__ Wthi,
    const u16* __restrict__ Wtlo, u16* __restrict__ Qh) {
    const int t = threadIdx.x;
    const int w = t >> 6, L = t & 63, lane16 = L & 15, quad = L >> 4;
    const int R0 = blockIdx.x * 64;
    const int row = R0 + w * 16 + lane16;
    const f32x4 z4 = {0.f, 0.f, 0.f, 0.f};
    f32x4 acc[4] = {z4, z4, z4, z4};
    union U8 { bf16x8 v; u16 s[8]; };
#pragma unroll
    for (int ks = 0; ks < 8; ++ks) {
        const float* fp = F + (size_t)row * 256 + ks * 32 + quad * 8;
        float4 x0 = *(const float4*)fp;
        float4 x1 = *(const float4*)(fp + 4);
        float xs[8] = {x0.x, x0.y, x0.z, x0.w, x1.x, x1.y, x1.z, x1.w};
        U8 ahi, alo;
#pragma unroll
        for (int j = 0; j < 8; ++j) {
            u16 h = f2bf(xs[j]);
            ahi.s[j] = h;
            alo.s[j] = f2bf(xs[j] - b2f(h));
        }
#pragma unroll
        for (int nt = 0; nt < 4; ++nt) {
            const int off = (nt * 16 + lane16) * 256 + ks * 32 + quad * 8;
            bf16x8 bh = ldg8b(Wthi + off);
            bf16x8 bl = ldg8b(Wtlo + off);
            acc[nt] = mfma_bf(ahi.v, bh, acc[nt]);
            acc[nt] = mfma_bf(alo.v, bh, acc[nt]);
            acc[nt] = mfma_bf(ahi.v, bl, acc[nt]);
        }
    }
    const int orow = R0 + w * 16 + quad * 4;
#pragma unroll
    for (int nt = 0; nt < 4; ++nt) {
        const int d = nt * 16 + lane16;
#pragma unroll
        for (int r = 0; r < 4; ++r) {
            const int p = orow + r;
            Qh[(size_t)p * 64 + (d ^ ((p & 7) << 3))] = f2h(acc[nt][r]);
        }
    }
}

// ---------- K2: lgl[p] = -log2( sum_q exp(Q_p . Q_q) ), p-tile 32, grid 1024 ----------
__global__ __launch_bounds__(256) void k2_suminv(
    const u16* __restrict__ Q, float* __restrict__ lgl) {
    const int t = threadIdx.x;
    const int w = t >> 6, L = t & 63, lane16 = L & 15, quad = L >> 4, l7 = lane16 & 7;
    const int bx = blockIdx.x;
    const int n = bx & 7, pb = bx >> 3;   // batch-per-XCD swizzle
    const int P0 = pb * 32;
    const u16* Qn = Q + (size_t)n * 4096 * 64;

    f16x8 ap[2][2];
#pragma unroll
    for (int st = 0; st < 2; ++st) {
        const int row = P0 + st * 16 + lane16;
        ap[st][0] = ldg8h(Qn + row * 64 + ((quad * 8) ^ (l7 * 8)));
        ap[st][1] = ldg8h(Qn + row * 64 + ((32 + quad * 8) ^ (l7 * 8)));
    }
    float sums[2][4];
#pragma unroll
    for (int st = 0; st < 2; ++st)
#pragma unroll
        for (int r = 0; r < 4; ++r) sums[st][r] = 0.f;

    const f32x4 z4 = {0.f, 0.f, 0.f, 0.f};
    for (int s = 0; s < 32; ++s) {
#pragma unroll
        for (int nt = 0; nt < 2; ++nt) {
            const int qr = w * 1024 + s * 32 + nt * 16 + lane16;
            f16x8 b0 = ldg8h(Qn + qr * 64 + ((quad * 8) ^ (l7 * 8)));
            f16x8 b1 = ldg8h(Qn + qr * 64 + ((32 + quad * 8) ^ (l7 * 8)));
#pragma unroll
            for (int st = 0; st < 2; ++st) {
                f32x4 z = z4;
                z = mfma_h(ap[st][0], b0, z);
                z = mfma_h(ap[st][1], b1, z);
                sums[st][0] += __expf(z[0]);
                sums[st][1] += __expf(z[1]);
                sums[st][2] += __expf(z[2]);
                sums[st][3] += __expf(z[3]);
            }
        }
    }
    __shared__ float red[4][32];
#pragma unroll
    for (int st = 0; st < 2; ++st)
#pragma unroll
        for (int r = 0; r < 4; ++r) {
            float v = sums[st][r];
            v += __shfl_xor(v, 1);
            v += __shfl_xor(v, 2);
            v += __shfl_xor(v, 4);
            v += __shfl_xor(v, 8);
            if (lane16 == 0) red[w][st * 16 + quad * 4 + r] = v;
        }
    __syncthreads();
    if (t < 32) {
        float tot = red[0][t] + red[1][t] + red[2][t] + red[3][t];
        lgl[n * 4096 + P0 + t] = -__log2f(tot);   // exp(z)/tot = exp2(z*log2e + lgl)
    }
}

// ---------- K3: Gt_sw[n][s][ch][p-swizzled] = bf16(F[n][p][ch]) ----------
__global__ __launch_bounds__(256) void k3_gt(
    const float* __restrict__ F, u16* __restrict__ Gt) {
    const int t = threadIdx.x;
    const int bx = blockIdx.x;                  // 512 = 8 n * 64 s
    const int n = bx >> 6, s = bx & 63;
    const int p0 = s * 64;
    __shared__ float tile[64][65];
    const float* Fn = F + (size_t)n * 4096 * 256;
    u16* Gn = Gt + (size_t)(n * 64 + s) * 16384;
#pragma unroll 1
    for (int ct = 0; ct < 4; ++ct) {
        const int c0 = ct * 64;
        if (ct > 0) __syncthreads();
#pragma unroll
        for (int k = 0; k < 16; ++k) {
            int idx = k * 256 + t;
            int r = idx >> 6, cc = idx & 63;
            tile[r][cc] = Fn[(size_t)(p0 + r) * 256 + c0 + cc];
        }
        __syncthreads();
#pragma unroll
        for (int k = 0; k < 2; ++k) {
            int u = k * 256 + t;
            int cc = u & 63, S = u >> 6;          // S in [0,8)
            int G = S ^ (cc & 7);
            u16 v[8];
#pragma unroll
            for (int j = 0; j < 8; ++j) v[j] = f2bf(tile[G * 8 + j][cc]);
            uint4 pk;
            pk.x = (u32)v[0] | ((u32)v[1] << 16);
            pk.y = (u32)v[2] | ((u32)v[3] << 16);
            pk.z = (u32)v[4] | ((u32)v[5] << 16);
            pk.w = (u32)v[6] | ((u32)v[7] << 16);
            *(uint4*)&Gn[(c0 + cc) * 64 + S * 8] = pk;
        }
    }
}

// ---------- K4: out tile 64q x 256ch, p-step 64 ----------
// v2: no LDS staging of Gt/Qp (zero intra-block reuse -> direct L2->reg loads,
// consumer-counted vmcnt, no barrier drains). Only sP (cross-wave transpose)
// stays in LDS, double-buffered -> ONE barrier per step.
__global__ __launch_bounds__(256, 2) void k4_attn(
    const u16* __restrict__ Q, const u16* __restrict__ Gt,
    const float* __restrict__ lgl, const float* __restrict__ mask,
    const float* __restrict__ ref, float* __restrict__ out) {
    const int t = threadIdx.x;
    const int w = t >> 6, L = t & 63, lane16 = L & 15, quad = L >> 4, l7 = lane16 & 7;
    const int bx = blockIdx.x;
    const int n = bx & 7, qb = bx >> 3;   // batch-per-XCD swizzle
    const int q0 = qb << 6;

    __shared__ u16 sP[2][4096];   // 16 KB: P' 64q x 64p, double-buffered

    const u16* Qn = Q + (size_t)n * 4096 * 64;
    const u16* Gtn = Gt + (size_t)n * 64 * 16384;
    const float* iln = lgl + n * 4096;

    // invariant B-frags: this block's 64 q-rows of Q
    f16x8 bq[4][2];
#pragma unroll
    for (int qt = 0; qt < 4; ++qt) {
        const int row = q0 + qt * 16 + lane16;
        bq[qt][0] = ldg8h(Qn + row * 64 + ((quad * 8) ^ (l7 * 8)));
        bq[qt][1] = ldg8h(Qn + row * 64 + ((32 + quad * 8) ^ (l7 * 8)));
    }

    // loop-invariant offsets
    // S-phase A rows (p-strip w), global offsets within a step's 64-row block
    const int sAg0 = (w * 16 + lane16) * 64 + ((quad * 8) ^ (l7 * 8));
    const int sAg1 = (w * 16 + lane16) * 64 + ((32 + quad * 8) ^ (l7 * 8));
    int wrP[4];
#pragma unroll
    for (int qt = 0; qt < 4; ++qt)
        wrP[qt] = (qt * 16 + lane16) * 64 +
                  ((w * 16 + 8 * (quad >> 1)) ^ (l7 * 8)) + 4 * (quad & 1);
    int rdP[4][2], gOf[4][2];
#pragma unroll
    for (int m = 0; m < 4; ++m)
#pragma unroll
        for (int h = 0; h < 2; ++h)
            rdP[m][h] = (m * 16 + lane16) * 64 + ((h * 32 + quad * 8) ^ (l7 * 8));
#pragma unroll
    for (int nt = 0; nt < 4; ++nt)
#pragma unroll
        for (int h = 0; h < 2; ++h)
            gOf[nt][h] = (w * 64 + nt * 16 + lane16) * 64 + ((h * 32 + quad * 8) ^ (l7 * 8));

    const f32x4 z4 = {0.f, 0.f, 0.f, 0.f};
    f32x4 acc[4][4];
#pragma unroll
    for (int a = 0; a < 4; ++a)
#pragma unroll
        for (int b = 0; b < 4; ++b) acc[a][b] = z4;

    // prologue: S(0) -> sP[0]
    {
        f16x8 a0 = ldg8h(Qn + sAg0);
        f16x8 a1 = ldg8h(Qn + sAg1);
        float4 il4 = *(const float4*)(iln + w * 16 + quad * 4);
        float lg[4] = {il4.x, il4.y, il4.z, il4.w};
#pragma unroll
        for (int qt = 0; qt < 4; ++qt) {
            f32x4 z = z4;
            z = mfma_h(a0, bq[qt][0], z);
            z = mfma_h(a1, bq[qt][1], z);
            uint2 pk;
            pk.x = pkbf2(__builtin_exp2f(__builtin_fmaf(z[0], LOG2E, lg[0])),
                         __builtin_exp2f(__builtin_fmaf(z[1], LOG2E, lg[1])));
            pk.y = pkbf2(__builtin_exp2f(__builtin_fmaf(z[2], LOG2E, lg[2])),
                         __builtin_exp2f(__builtin_fmaf(z[3], LOG2E, lg[3])));
            *(uint2*)&sP[0][wrP[qt]] = pk;
        }
    }
    __syncthreads();

#pragma unroll 1
    for (int i = 0; i < 64; ++i) {
        const u16* sPc = &sP[i & 1][0];
        u16* sPn = &sP[(i + 1) & 1][0];
        const u16* gstep = Gtn + (size_t)i * 16384;
        // ---- PV(i): af from sP (LDS), bb direct from global (L2-hot) ----
#pragma unroll
        for (int h = 0; h < 2; ++h) {
            bf16x8 af[4], bb[4];
#pragma unroll
            for (int m = 0; m < 4; ++m) af[m] = ldg8b(&sPc[rdP[m][h]]);
#pragma unroll
            for (int nt = 0; nt < 4; ++nt) bb[nt] = ldg8b(gstep + gOf[nt][h]);
#pragma unroll
            for (int nt = 0; nt < 4; ++nt)
#pragma unroll
                for (int m = 0; m < 4; ++m)
                    acc[m][nt] = mfma_bf(af[m], bb[nt], acc[m][nt]);
        }
        // ---- S(i+1): Qp direct from global, write sP[other buf] ----
        if (i + 1 < 64) {
            f16x8 a0 = ldg8h(Qn + (i + 1) * 4096 + sAg0);
            f16x8 a1 = ldg8h(Qn + (i + 1) * 4096 + sAg1);
            float4 il4 = *(const float4*)(iln + (i + 1) * 64 + w * 16 + quad * 4);
            float lg[4] = {il4.x, il4.y, il4.z, il4.w};
#pragma unroll
            for (int qt = 0; qt < 4; ++qt) {
                f32x4 z = z4;
                z = mfma_h(a0, bq[qt][0], z);
                z = mfma_h(a1, bq[qt][1], z);
                uint2 pk;
                pk.x = pkbf2(__builtin_exp2f(__builtin_fmaf(z[0], LOG2E, lg[0])),
                             __builtin_exp2f(__builtin_fmaf(z[1], LOG2E, lg[1])));
                pk.y = pkbf2(__builtin_exp2f(__builtin_fmaf(z[2], LOG2E, lg[2])),
                             __builtin_exp2f(__builtin_fmaf(z[3], LOG2E, lg[3])));
                *(uint2*)&sPn[wrP[qt]] = pk;
            }
        }
        __syncthreads();   // one barrier/step: publishes sP[next], fences buf reuse
    }

    // ---- epilogue: replicate the reference's reshape scramble ----
    // out pixel = ch*16 + (qb>>2), out channel = (qb&3)*64 + q_local
    const int tb = qb >> 2;
    const int cb = (qb & 3) * 64;
    const float* maskn = mask + n * 4096;
    const float* refn = ref + (size_t)n * 4096 * 256;
    float* outn = out + (size_t)n * 4096 * 512;
#pragma unroll
    for (int nt = 0; nt < 4; ++nt) {
        const int ch = w * 64 + nt * 16 + lane16;
        const int pixel = ch * 16 + tb;
        const float m = maskn[pixel];
#pragma unroll
        for (int mt = 0; mt < 4; ++mt) {
            const int c4 = cb + mt * 16 + quad * 4;
            float4 r4 = *(const float4*)(refn + (size_t)pixel * 256 + c4);
            float a0 = acc[mt][nt][0], a1 = acc[mt][nt][1];
            float a2 = acc[mt][nt][2], a3 = acc[mt][nt][3];
            float4 a4 = {a0, a1, a2, a3};
            float4 bl4 = {m * a0 + (1.f - m) * r4.x,
                          m * a1 + (1.f - m) * r4.y,
                          m * a2 + (1.f - m) * r4.z,
                          m * a3 + (1.f - m) * r4.w};
            *(float4*)(outn + (size_t)pixel * 512 + 256 + c4) = a4;   // src_att
            *(float4*)(outn + (size_t)pixel * 512 + c4) = bl4;        // ex_guide_flow
        }
    }
}

extern "C" void kernel_launch(void* const* d_in, const int* in_sizes, int n_in,
                              void* d_out, int out_size, void* d_ws, size_t ws_size,
                              hipStream_t stream) {
    const float* mask = (const float*)d_in[0];   // (8,64,64) f32
    const float* F    = (const float*)d_in[1];   // (8,64,64,256) f32
    const float* ref  = (const float*)d_in[2];   // (8,64,64,256) f32
    const float* Wq   = (const float*)d_in[3];   // (256,64) f32
    float* out = (float*)d_out;                  // (8,64,64,512) f32
    char* ws = (char*)d_ws;

    u16*   Wthi = (u16*)ws;                                     // 32 KB
    u16*   Wtlo = (u16*)(ws + 32768);                           // 32 KB
    u16*   Qh   = (u16*)(ws + 65536);                           // 4 MB (fp16, swizzled)
    float* lgl  = (float*)(ws + 65536 + 4194304);               // 128 KB (-log2 of denom)
    u16*   Gt   = (u16*)(ws + 65536 + 4194304 + 131072);        // 16 MB (bf16, swizzled)

    k0_wt    <<<64,   256, 0, stream>>>(Wq, Wthi, Wtlo);
    k1_query <<<512,  256, 0, stream>>>(F, Wthi, Wtlo, Qh);
    k2_suminv<<<1024, 256, 0, stream>>>(Qh, lgl);
    k3_gt    <<<512,  256, 0, stream>>>(F, Gt);
    k4_attn  <<<512,  256, 0, stream>>>(Qh, Gt, lgl, mask, ref, out);
}

// Round 2
// 286.479 us; speedup vs baseline: 1.1710x; 1.1710x over previous
//
#include <hip/hip_runtime.h>

typedef unsigned short u16;
typedef unsigned int u32;
typedef __attribute__((ext_vector_type(8))) __bf16 bf16x8;
typedef __attribute__((ext_vector_type(8))) _Float16 f16x8;
typedef __attribute__((ext_vector_type(4))) float f32x4;

// ---------- helpers ----------
__device__ __forceinline__ float b2f(u16 b) {
    union { u32 u; float f; } v; v.u = ((u32)b) << 16; return v.f;
}
__device__ __forceinline__ u16 f2bf(float f) {
    union { float f; u32 u; } v; v.f = f;
    u32 u = v.u;
    return (u16)((u + 0x7fffu + ((u >> 16) & 1u)) >> 16);  // RNE
}
__device__ __forceinline__ u16 f2h(float f) {
    _Float16 h = (_Float16)f;
    return __builtin_bit_cast(u16, h);
}
// native RNE cvt pair -> packed u32 (compiler emits v_cvt_pk_bf16_f32)
__device__ __forceinline__ u32 pkbf2(float a, float b) {
    u16 x = __builtin_bit_cast(u16, (__bf16)a);
    u16 y = __builtin_bit_cast(u16, (__bf16)b);
    return (u32)x | ((u32)y << 16);
}
__device__ __forceinline__ bf16x8 ldg8b(const u16* p) {
    uint4 v = *(const uint4*)p;
    return __builtin_bit_cast(bf16x8, v);
}
__device__ __forceinline__ f16x8 ldg8h(const u16* p) {
    uint4 v = *(const uint4*)p;
    return __builtin_bit_cast(f16x8, v);
}
__device__ __forceinline__ f32x4 mfma_bf(bf16x8 a, bf16x8 b, f32x4 c) {
    return __builtin_amdgcn_mfma_f32_16x16x32_bf16(a, b, c, 0, 0, 0);
}
__device__ __forceinline__ f32x4 mfma_h(f16x8 a, f16x8 b, f32x4 c) {
    return __builtin_amdgcn_mfma_f32_16x16x32_f16(a, b, c, 0, 0, 0);
}
// async global->LDS: lds dest = wave-uniform base + lane*16
__device__ __forceinline__ void gld16(const u16* g, u16* l) {
    __builtin_amdgcn_global_load_lds(
        (const __attribute__((address_space(1))) u32*)g,
        (__attribute__((address_space(3))) u32*)l, 16, 0, 0);
}

#define LOG2E 1.44269504088896340736f

// Q global layout: per batch, row p (4096): 64 fp16, elem slot = d ^ ((p&7)*8)
// Gt global layout: per (n, step s of 64 p): 16384 elems: ch*64 + ((pp&~7)^((ch&7)*8)) + (pp&7)

// ---------- K0: hi/lo bf16 split of W, transposed: Wt[d][c] ----------
__global__ void k0_wt(const float* __restrict__ Wq,
                      u16* __restrict__ Wthi, u16* __restrict__ Wtlo) {
    int idx = blockIdx.x * 256 + threadIdx.x;   // 64 blocks -> 16384
    int c = idx >> 6, d = idx & 63;
    float w = Wq[idx];
    u16 hi = f2bf(w);
    float rem = w - b2f(hi);
    Wthi[d * 256 + c] = hi;
    Wtlo[d * 256 + c] = f2bf(rem);
}

// ---------- K1: Q = F*W (hi/lo split MFMA), fp16 out, XOR-swizzled rows ----------
__global__ __launch_bounds__(256) void k1_query(
    const float* __restrict__ F, const u16* __restrict__ Wthi,
    const u16* __restrict__ Wtlo, u16* __restrict__ Qh) {
    const int t = threadIdx.x;
    const int w = t >> 6, L = t & 63, lane16 = L & 15, quad = L >> 4;
    const int R0 = blockIdx.x * 64;
    const int row = R0 + w * 16 + lane16;
    const f32x4 z4 = {0.f, 0.f, 0.f, 0.f};
    f32x4 acc[4] = {z4, z4, z4, z4};
    union U8 { bf16x8 v; u16 s[8]; };
#pragma unroll
    for (int ks = 0; ks < 8; ++ks) {
        const float* fp = F + (size_t)row * 256 + ks * 32 + quad * 8;
        float4 x0 = *(const float4*)fp;
        float4 x1 = *(const float4*)(fp + 4);
        float xs[8] = {x0.x, x0.y, x0.z, x0.w, x1.x, x1.y, x1.z, x1.w};
        U8 ahi, alo;
#pragma unroll
        for (int j = 0; j < 8; ++j) {
            u16 h = f2bf(xs[j]);
            ahi.s[j] = h;
            alo.s[j] = f2bf(xs[j] - b2f(h));
        }
#pragma unroll
        for (int nt = 0; nt < 4; ++nt) {
            const int off = (nt * 16 + lane16) * 256 + ks * 32 + quad * 8;
            bf16x8 bh = ldg8b(Wthi + off);
            bf16x8 bl = ldg8b(Wtlo + off);
            acc[nt] = mfma_bf(ahi.v, bh, acc[nt]);
            acc[nt] = mfma_bf(alo.v, bh, acc[nt]);
            acc[nt] = mfma_bf(ahi.v, bl, acc[nt]);
        }
    }
    const int orow = R0 + w * 16 + quad * 4;
#pragma unroll
    for (int nt = 0; nt < 4; ++nt) {
        const int d = nt * 16 + lane16;
#pragma unroll
        for (int r = 0; r < 4; ++r) {
            const int p = orow + r;
            Qh[(size_t)p * 64 + (d ^ ((p & 7) << 3))] = f2h(acc[nt][r]);
        }
    }
}

// ---------- K2: lgl[p] = -log2( sum_q exp(Q_p . Q_q) ), p-tile 32, grid 1024 ----------
__global__ __launch_bounds__(256) void k2_suminv(
    const u16* __restrict__ Q, float* __restrict__ lgl) {
    const int t = threadIdx.x;
    const int w = t >> 6, L = t & 63, lane16 = L & 15, quad = L >> 4, l7 = lane16 & 7;
    const int bx = blockIdx.x;
    const int n = bx & 7, pb = bx >> 3;   // batch-per-XCD swizzle
    const int P0 = pb * 32;
    const u16* Qn = Q + (size_t)n * 4096 * 64;

    f16x8 ap[2][2];
#pragma unroll
    for (int st = 0; st < 2; ++st) {
        const int row = P0 + st * 16 + lane16;
        ap[st][0] = ldg8h(Qn + row * 64 + ((quad * 8) ^ (l7 * 8)));
        ap[st][1] = ldg8h(Qn + row * 64 + ((32 + quad * 8) ^ (l7 * 8)));
    }
    float sums[2][4];
#pragma unroll
    for (int st = 0; st < 2; ++st)
#pragma unroll
        for (int r = 0; r < 4; ++r) sums[st][r] = 0.f;

    const f32x4 z4 = {0.f, 0.f, 0.f, 0.f};
    for (int s = 0; s < 32; ++s) {
#pragma unroll
        for (int nt = 0; nt < 2; ++nt) {
            const int qr = w * 1024 + s * 32 + nt * 16 + lane16;
            f16x8 b0 = ldg8h(Qn + qr * 64 + ((quad * 8) ^ (l7 * 8)));
            f16x8 b1 = ldg8h(Qn + qr * 64 + ((32 + quad * 8) ^ (l7 * 8)));
#pragma unroll
            for (int st = 0; st < 2; ++st) {
                f32x4 z = z4;
                z = mfma_h(ap[st][0], b0, z);
                z = mfma_h(ap[st][1], b1, z);
                sums[st][0] += __expf(z[0]);
                sums[st][1] += __expf(z[1]);
                sums[st][2] += __expf(z[2]);
                sums[st][3] += __expf(z[3]);
            }
        }
    }
    __shared__ float red[4][32];
#pragma unroll
    for (int st = 0; st < 2; ++st)
#pragma unroll
        for (int r = 0; r < 4; ++r) {
            float v = sums[st][r];
            v += __shfl_xor(v, 1);
            v += __shfl_xor(v, 2);
            v += __shfl_xor(v, 4);
            v += __shfl_xor(v, 8);
            if (lane16 == 0) red[w][st * 16 + quad * 4 + r] = v;
        }
    __syncthreads();
    if (t < 32) {
        float tot = red[0][t] + red[1][t] + red[2][t] + red[3][t];
        lgl[n * 4096 + P0 + t] = -__log2f(tot);   // exp(z)/tot = exp2(z*log2e + lgl)
    }
}

// ---------- K3: Gt_sw[n][s][ch][p-swizzled] = bf16(F[n][p][ch]) ----------
__global__ __launch_bounds__(256) void k3_gt(
    const float* __restrict__ F, u16* __restrict__ Gt) {
    const int t = threadIdx.x;
    const int bx = blockIdx.x;                  // 512 = 8 n * 64 s
    const int n = bx >> 6, s = bx & 63;
    const int p0 = s * 64;
    __shared__ float tile[64][65];
    const float* Fn = F + (size_t)n * 4096 * 256;
    u16* Gn = Gt + (size_t)(n * 64 + s) * 16384;
#pragma unroll 1
    for (int ct = 0; ct < 4; ++ct) {
        const int c0 = ct * 64;
        if (ct > 0) __syncthreads();
#pragma unroll
        for (int k = 0; k < 16; ++k) {
            int idx = k * 256 + t;
            int r = idx >> 6, cc = idx & 63;
            tile[r][cc] = Fn[(size_t)(p0 + r) * 256 + c0 + cc];
        }
        __syncthreads();
#pragma unroll
        for (int k = 0; k < 2; ++k) {
            int u = k * 256 + t;
            int cc = u & 63, S = u >> 6;          // S in [0,8)
            int G = S ^ (cc & 7);
            u16 v[8];
#pragma unroll
            for (int j = 0; j < 8; ++j) v[j] = f2bf(tile[G * 8 + j][cc]);
            uint4 pk;
            pk.x = (u32)v[0] | ((u32)v[1] << 16);
            pk.y = (u32)v[2] | ((u32)v[3] << 16);
            pk.z = (u32)v[4] | ((u32)v[5] << 16);
            pk.w = (u32)v[6] | ((u32)v[7] << 16);
            *(uint4*)&Gn[(c0 + cc) * 64 + S * 8] = pk;
        }
    }
}

// ---------- K4: out tile 64q x 256ch, p-step 64 ----------
// v3: T3+T4 structure. sGt double-buffered DMA (global_load_lds), prefetch
// distance = one full step; sP double-buffered; ONE raw s_barrier per step
// with explicit lgkmcnt(0) only (NO vmcnt(0) drain -> next-step DMA stays in
// flight across the barrier). S-phase operands register-prefetched (T14).
// Invariants (verified from index math):
//  - sGt/Qp staging is wave-self-contained: wave w DMAs and reads only
//    [w*4096, (w+1)*4096) -> DMA completion needs only the issuing wave's
//    vmcnt, no cross-wave fence.
//  - vmcnt queue order per iter must be [DMA x8 (old), na/nil x3 (new)]:
//    the compiler's wait for na/nil at the next S-phase is then vmcnt(0),
//    which drains the current sGt DMA before PV reads it. Pinned with
//    sched_barrier(0).
//  - only sP needs barrier visibility (cross-wave transpose) -> lgkmcnt(0)
//    before each raw barrier.
__global__ __launch_bounds__(256, 2) void k4_attn(
    const u16* __restrict__ Q, const u16* __restrict__ Gt,
    const float* __restrict__ lgl, const float* __restrict__ mask,
    const float* __restrict__ ref, float* __restrict__ out) {
    const int t = threadIdx.x;
    const int w = t >> 6, L = t & 63, lane16 = L & 15, quad = L >> 4, l7 = lane16 & 7;
    const int bx = blockIdx.x;
    const int n = bx & 7, qb = bx >> 3;   // batch-per-XCD swizzle
    const int q0 = qb << 6;

    __shared__ u16 sGt[2][16384];  // 64 KB: step's 256ch x 64p (swizzled), dbuf
    __shared__ u16 sP[2][4096];    // 16 KB: P' 64q x 64p (swizzled), dbuf

    const u16* Qn = Q + (size_t)n * 4096 * 64;
    const u16* Gtn = Gt + (size_t)n * 64 * 16384;
    const float* iln = lgl + n * 4096;

    // invariant B-frags: this block's 64 q-rows of Q
    f16x8 bq[4][2];
#pragma unroll
    for (int qt = 0; qt < 4; ++qt) {
        const int row = q0 + qt * 16 + lane16;
        bq[qt][0] = ldg8h(Qn + row * 64 + ((quad * 8) ^ (l7 * 8)));
        bq[qt][1] = ldg8h(Qn + row * 64 + ((32 + quad * 8) ^ (l7 * 8)));
    }

    // loop-invariant offsets
    const int sAg0 = (w * 16 + lane16) * 64 + ((quad * 8) ^ (l7 * 8));
    const int sAg1 = (w * 16 + lane16) * 64 + ((32 + quad * 8) ^ (l7 * 8));
    int wrP[4];
#pragma unroll
    for (int qt = 0; qt < 4; ++qt)
        wrP[qt] = (qt * 16 + lane16) * 64 +
                  ((w * 16 + 8 * (quad >> 1)) ^ (l7 * 8)) + 4 * (quad & 1);
    int rdP[4][2], sOf[4][2];
#pragma unroll
    for (int m = 0; m < 4; ++m)
#pragma unroll
        for (int h = 0; h < 2; ++h)
            rdP[m][h] = (m * 16 + lane16) * 64 + ((h * 32 + quad * 8) ^ (l7 * 8));
#pragma unroll
    for (int nt = 0; nt < 4; ++nt)
#pragma unroll
        for (int h = 0; h < 2; ++h)
            sOf[nt][h] = (w * 64 + nt * 16 + lane16) * 64 + ((h * 32 + quad * 8) ^ (l7 * 8));
    const int dl = L * 8;          // DMA lane offset (elems)

    const f32x4 z4 = {0.f, 0.f, 0.f, 0.f};
    f32x4 acc[4][4];
#pragma unroll
    for (int a = 0; a < 4; ++a)
#pragma unroll
        for (int b = 0; b < 4; ++b) acc[a][b] = z4;

    // ---- prologue ----
    // S(0) -> sP[0] (direct loads; compiler drains them at the MFMAs)
    {
        f16x8 a0 = ldg8h(Qn + sAg0);
        f16x8 a1 = ldg8h(Qn + sAg1);
        float4 il4 = *(const float4*)(iln + w * 16 + quad * 4);
        float lg[4] = {il4.x, il4.y, il4.z, il4.w};
#pragma unroll
        for (int qt = 0; qt < 4; ++qt) {
            f32x4 z = z4;
            z = mfma_h(a0, bq[qt][0], z);
            z = mfma_h(a1, bq[qt][1], z);
            uint2 pk;
            pk.x = pkbf2(__builtin_exp2f(__builtin_fmaf(z[0], LOG2E, lg[0])),
                         __builtin_exp2f(__builtin_fmaf(z[1], LOG2E, lg[1])));
            pk.y = pkbf2(__builtin_exp2f(__builtin_fmaf(z[2], LOG2E, lg[2])),
                         __builtin_exp2f(__builtin_fmaf(z[3], LOG2E, lg[3])));
            *(uint2*)&sP[0][wrP[qt]] = pk;
        }
    }
    __builtin_amdgcn_sched_barrier(0);
    // DMA sGt[0] <- Gt(0)  (oldest in vmcnt queue)
#pragma unroll
    for (int j = 0; j < 8; ++j) {
        const int c = w * 8 + j;
        gld16(Gtn + c * 512 + dl, &sGt[0][c * 512]);
    }
    __builtin_amdgcn_sched_barrier(0);
    // register-prefetch S(1) operands (newest in vmcnt queue)
    f16x8 na0 = ldg8h(Qn + 4096 + sAg0);
    f16x8 na1 = ldg8h(Qn + 4096 + sAg1);
    float4 nil4 = *(const float4*)(iln + 64 + w * 16 + quad * 4);
    __builtin_amdgcn_sched_barrier(0);
    asm volatile("s_waitcnt lgkmcnt(0)" ::: "memory");
    __builtin_amdgcn_s_barrier();

#pragma unroll 1
    for (int i = 0; i < 64; ++i) {
        const int cur = i & 1, nxt = cur ^ 1;
        if (i + 1 < 64) {
            // ---- S(i+1): preloaded operands; compiler's vmcnt wait here
            //      drains [DMA(cur) x8, na x3] (na is newest -> vmcnt(0)) ----
            float lg[4] = {nil4.x, nil4.y, nil4.z, nil4.w};
#pragma unroll
            for (int qt = 0; qt < 4; ++qt) {
                f32x4 z = z4;
                z = mfma_h(na0, bq[qt][0], z);
                z = mfma_h(na1, bq[qt][1], z);
                uint2 pk;
                pk.x = pkbf2(__builtin_exp2f(__builtin_fmaf(z[0], LOG2E, lg[0])),
                             __builtin_exp2f(__builtin_fmaf(z[1], LOG2E, lg[1])));
                pk.y = pkbf2(__builtin_exp2f(__builtin_fmaf(z[2], LOG2E, lg[2])),
                             __builtin_exp2f(__builtin_fmaf(z[3], LOG2E, lg[3])));
                *(uint2*)&sP[nxt][wrP[qt]] = pk;
            }
            __builtin_amdgcn_sched_barrier(0);
            // ---- DMA sGt[nxt] <- Gt(i+1): stays in flight across the barrier,
            //      drained by NEXT iteration's S-phase vmcnt wait ----
            const u16* gsrc = Gtn + (size_t)(i + 1) * 16384;
#pragma unroll
            for (int j = 0; j < 8; ++j) {
                const int c = w * 8 + j;
                gld16(gsrc + c * 512 + dl, &sGt[nxt][c * 512]);
            }
            __builtin_amdgcn_sched_barrier(0);
            // ---- register-prefetch S(i+2) operands (must be newer than DMA) ----
            if (i + 2 < 64) {
                na0 = ldg8h(Qn + (size_t)(i + 2) * 4096 + sAg0);
                na1 = ldg8h(Qn + (size_t)(i + 2) * 4096 + sAg1);
                nil4 = *(const float4*)(iln + (i + 2) * 64 + w * 16 + quad * 4);
            }
            __builtin_amdgcn_sched_barrier(0);
        } else {
            // last step: no S-phase wait happened -> drain sGt[cur] DMA explicitly
            asm volatile("s_waitcnt vmcnt(0)" ::: "memory");
        }
        // ---- PV(i): LDS reads (wave-local sGt region + published sP) ----
#pragma unroll
        for (int h = 0; h < 2; ++h) {
            bf16x8 af[4], bb[4];
#pragma unroll
            for (int m = 0; m < 4; ++m) af[m] = ldg8b(&sP[cur][rdP[m][h]]);
#pragma unroll
            for (int nt = 0; nt < 4; ++nt) bb[nt] = ldg8b(&sGt[cur][sOf[nt][h]]);
#pragma unroll
            for (int nt = 0; nt < 4; ++nt)
#pragma unroll
                for (int m = 0; m < 4; ++m)
                    acc[m][nt] = mfma_bf(af[m], bb[nt], acc[m][nt]);
        }
        // one raw barrier/step: publishes sP[nxt]; NO vmcnt drain (DMA in flight)
        asm volatile("s_waitcnt lgkmcnt(0)" ::: "memory");
        __builtin_amdgcn_s_barrier();
    }

    // ---- epilogue: replicate the reference's reshape scramble ----
    // out pixel = ch*16 + (qb>>2), out channel = (qb&3)*64 + q_local
    const int tb = qb >> 2;
    const int cb = (qb & 3) * 64;
    const float* maskn = mask + n * 4096;
    const float* refn = ref + (size_t)n * 4096 * 256;
    float* outn = out + (size_t)n * 4096 * 512;
#pragma unroll
    for (int nt = 0; nt < 4; ++nt) {
        const int ch = w * 64 + nt * 16 + lane16;
        const int pixel = ch * 16 + tb;
        const float m = maskn[pixel];
#pragma unroll
        for (int mt = 0; mt < 4; ++mt) {
            const int c4 = cb + mt * 16 + quad * 4;
            float4 r4 = *(const float4*)(refn + (size_t)pixel * 256 + c4);
            float a0 = acc[mt][nt][0], a1 = acc[mt][nt][1];
            float a2 = acc[mt][nt][2], a3 = acc[mt][nt][3];
            float4 a4 = {a0, a1, a2, a3};
            float4 bl4 = {m * a0 + (1.f - m) * r4.x,
                          m * a1 + (1.f - m) * r4.y,
                          m * a2 + (1.f - m) * r4.z,
                          m * a3 + (1.f - m) * r4.w};
            *(float4*)(outn + (size_t)pixel * 512 + 256 + c4) = a4;   // src_att
            *(float4*)(outn + (size_t)pixel * 512 + c4) = bl4;        // ex_guide_flow
        }
    }
}

extern "C" void kernel_launch(void* const* d_in, const int* in_sizes, int n_in,
                              void* d_out, int out_size, void* d_ws, size_t ws_size,
                              hipStream_t stream) {
    const float* mask = (const float*)d_in[0];   // (8,64,64) f32
    const float* F    = (const float*)d_in[1];   // (8,64,64,256) f32
    const float* ref  = (const float*)d_in[2];   // (8,64,64,256) f32
    const float* Wq   = (const float*)d_in[3];   // (256,64) f32
    float* out = (float*)d_out;                  // (8,64,64,512) f32
    char* ws = (char*)d_ws;

    u16*   Wthi = (u16*)ws;                                     // 32 KB
    u16*   Wtlo = (u16*)(ws + 32768);                           // 32 KB
    u16*   Qh   = (u16*)(ws + 65536);                           // 4 MB (fp16, swizzled)
    float* lgl  = (float*)(ws + 65536 + 4194304);               // 128 KB (-log2 of denom)
    u16*   Gt   = (u16*)(ws + 65536 + 4194304 + 131072);        // 16 MB (bf16, swizzled)

    k0_wt    <<<64,   256, 0, stream>>>(Wq, Wthi, Wtlo);
    k1_query <<<512,  256, 0, stream>>>(F, Wthi, Wtlo, Qh);
    k2_suminv<<<1024, 256, 0, stream>>>(Qh, lgl);
    k3_gt    <<<512,  256, 0, stream>>>(F, Gt);
    k4_attn  <<<512,  256, 0, stream>>>(Qh, Gt, lgl, mask, ref, out);
}

// Round 3
// 279.217 us; speedup vs baseline: 1.2015x; 1.0260x over previous
//
#include <hip/hip_runtime.h>

typedef unsigned short u16;
typedef unsigned int u32;
typedef __attribute__((ext_vector_type(8))) __bf16 bf16x8;
typedef __attribute__((ext_vector_type(8))) _Float16 f16x8;
typedef __attribute__((ext_vector_type(4))) float f32x4;

// ---------- helpers ----------
__device__ __forceinline__ float b2f(u16 b) {
    union { u32 u; float f; } v; v.u = ((u32)b) << 16; return v.f;
}
__device__ __forceinline__ u16 f2bf(float f) {
    union { float f; u32 u; } v; v.f = f;
    u32 u = v.u;
    return (u16)((u + 0x7fffu + ((u >> 16) & 1u)) >> 16);  // RNE
}
__device__ __forceinline__ u16 f2h(float f) {
    _Float16 h = (_Float16)f;
    return __builtin_bit_cast(u16, h);
}
// native RNE cvt pair -> packed u32 (compiler emits v_cvt_pk_bf16_f32)
__device__ __forceinline__ u32 pkbf2(float a, float b) {
    u16 x = __builtin_bit_cast(u16, (__bf16)a);
    u16 y = __builtin_bit_cast(u16, (__bf16)b);
    return (u32)x | ((u32)y << 16);
}
__device__ __forceinline__ bf16x8 ldg8b(const u16* p) {
    uint4 v = *(const uint4*)p;
    return __builtin_bit_cast(bf16x8, v);
}
__device__ __forceinline__ f16x8 ldg8h(const u16* p) {
    uint4 v = *(const uint4*)p;
    return __builtin_bit_cast(f16x8, v);
}
__device__ __forceinline__ f32x4 mfma_bf(bf16x8 a, bf16x8 b, f32x4 c) {
    return __builtin_amdgcn_mfma_f32_16x16x32_bf16(a, b, c, 0, 0, 0);
}
__device__ __forceinline__ f32x4 mfma_h(f16x8 a, f16x8 b, f32x4 c) {
    return __builtin_amdgcn_mfma_f32_16x16x32_f16(a, b, c, 0, 0, 0);
}

#define LOG2E 1.44269504088896340736f

// Q global layout: per batch, row p (4096): 64 fp16, elem slot = d ^ ((p&7)*8)
// Gt global layout: per (n, step s of 64 p): 16384 elems: ch*64 + ((pp&~7)^((ch&7)*8)) + (pp&7)

// ---------- K0: hi/lo bf16 split of W, transposed: Wt[d][c] ----------
__global__ void k0_wt(const float* __restrict__ Wq,
                      u16* __restrict__ Wthi, u16* __restrict__ Wtlo) {
    int idx = blockIdx.x * 256 + threadIdx.x;   // 64 blocks -> 16384
    int c = idx >> 6, d = idx & 63;
    float w = Wq[idx];
    u16 hi = f2bf(w);
    float rem = w - b2f(hi);
    Wthi[d * 256 + c] = hi;
    Wtlo[d * 256 + c] = f2bf(rem);
}

// ---------- K1: Q = F*W (hi/lo split MFMA), fp16 out, XOR-swizzled rows ----------
__global__ __launch_bounds__(256) void k1_query(
    const float* __restrict__ F, const u16* __restrict__ Wthi,
    const u16* __restrict__ Wtlo, u16* __restrict__ Qh) {
    const int t = threadIdx.x;
    const int w = t >> 6, L = t & 63, lane16 = L & 15, quad = L >> 4;
    const int R0 = blockIdx.x * 64;
    const int row = R0 + w * 16 + lane16;
    const f32x4 z4 = {0.f, 0.f, 0.f, 0.f};
    f32x4 acc[4] = {z4, z4, z4, z4};
    union U8 { bf16x8 v; u16 s[8]; };
#pragma unroll
    for (int ks = 0; ks < 8; ++ks) {
        const float* fp = F + (size_t)row * 256 + ks * 32 + quad * 8;
        float4 x0 = *(const float4*)fp;
        float4 x1 = *(const float4*)(fp + 4);
        float xs[8] = {x0.x, x0.y, x0.z, x0.w, x1.x, x1.y, x1.z, x1.w};
        U8 ahi, alo;
#pragma unroll
        for (int j = 0; j < 8; ++j) {
            u16 h = f2bf(xs[j]);
            ahi.s[j] = h;
            alo.s[j] = f2bf(xs[j] - b2f(h));
        }
#pragma unroll
        for (int nt = 0; nt < 4; ++nt) {
            const int off = (nt * 16 + lane16) * 256 + ks * 32 + quad * 8;
            bf16x8 bh = ldg8b(Wthi + off);
            bf16x8 bl = ldg8b(Wtlo + off);
            acc[nt] = mfma_bf(ahi.v, bh, acc[nt]);
            acc[nt] = mfma_bf(alo.v, bh, acc[nt]);
            acc[nt] = mfma_bf(ahi.v, bl, acc[nt]);
        }
    }
    const int orow = R0 + w * 16 + quad * 4;
#pragma unroll
    for (int nt = 0; nt < 4; ++nt) {
        const int d = nt * 16 + lane16;
#pragma unroll
        for (int r = 0; r < 4; ++r) {
            const int p = orow + r;
            Qh[(size_t)p * 64 + (d ^ ((p & 7) << 3))] = f2h(acc[nt][r]);
        }
    }
}

// ---------- K2: lgl[p] = -log2( sum_q exp(Q_p . Q_q) ), p-tile 32, grid 1024 ----------
__global__ __launch_bounds__(256) void k2_suminv(
    const u16* __restrict__ Q, float* __restrict__ lgl) {
    const int t = threadIdx.x;
    const int w = t >> 6, L = t & 63, lane16 = L & 15, quad = L >> 4, l7 = lane16 & 7;
    const int bx = blockIdx.x;
    const int n = bx & 7, pb = bx >> 3;   // batch-per-XCD swizzle
    const int P0 = pb * 32;
    const u16* Qn = Q + (size_t)n * 4096 * 64;

    f16x8 ap[2][2];
#pragma unroll
    for (int st = 0; st < 2; ++st) {
        const int row = P0 + st * 16 + lane16;
        ap[st][0] = ldg8h(Qn + row * 64 + ((quad * 8) ^ (l7 * 8)));
        ap[st][1] = ldg8h(Qn + row * 64 + ((32 + quad * 8) ^ (l7 * 8)));
    }
    float sums[2][4];
#pragma unroll
    for (int st = 0; st < 2; ++st)
#pragma unroll
        for (int r = 0; r < 4; ++r) sums[st][r] = 0.f;

    const f32x4 z4 = {0.f, 0.f, 0.f, 0.f};
    for (int s = 0; s < 32; ++s) {
#pragma unroll
        for (int nt = 0; nt < 2; ++nt) {
            const int qr = w * 1024 + s * 32 + nt * 16 + lane16;
            f16x8 b0 = ldg8h(Qn + qr * 64 + ((quad * 8) ^ (l7 * 8)));
            f16x8 b1 = ldg8h(Qn + qr * 64 + ((32 + quad * 8) ^ (l7 * 8)));
#pragma unroll
            for (int st = 0; st < 2; ++st) {
                f32x4 z = z4;
                z = mfma_h(ap[st][0], b0, z);
                z = mfma_h(ap[st][1], b1, z);
                sums[st][0] += __expf(z[0]);
                sums[st][1] += __expf(z[1]);
                sums[st][2] += __expf(z[2]);
                sums[st][3] += __expf(z[3]);
            }
        }
    }
    __shared__ float red[4][32];
#pragma unroll
    for (int st = 0; st < 2; ++st)
#pragma unroll
        for (int r = 0; r < 4; ++r) {
            float v = sums[st][r];
            v += __shfl_xor(v, 1);
            v += __shfl_xor(v, 2);
            v += __shfl_xor(v, 4);
            v += __shfl_xor(v, 8);
            if (lane16 == 0) red[w][st * 16 + quad * 4 + r] = v;
        }
    __syncthreads();
    if (t < 32) {
        float tot = red[0][t] + red[1][t] + red[2][t] + red[3][t];
        lgl[n * 4096 + P0 + t] = -__log2f(tot);   // exp(z)/tot = exp2(z*log2e + lgl)
    }
}

// ---------- K3: Gt_sw[n][s][ch][p-swizzled] = bf16(F[n][p][ch]) ----------
__global__ __launch_bounds__(256) void k3_gt(
    const float* __restrict__ F, u16* __restrict__ Gt) {
    const int t = threadIdx.x;
    const int bx = blockIdx.x;                  // 512 = 8 n * 64 s
    const int n = bx >> 6, s = bx & 63;
    const int p0 = s * 64;
    __shared__ float tile[64][65];
    const float* Fn = F + (size_t)n * 4096 * 256;
    u16* Gn = Gt + (size_t)(n * 64 + s) * 16384;
#pragma unroll 1
    for (int ct = 0; ct < 4; ++ct) {
        const int c0 = ct * 64;
        if (ct > 0) __syncthreads();
#pragma unroll
        for (int k = 0; k < 16; ++k) {
            int idx = k * 256 + t;
            int r = idx >> 6, cc = idx & 63;
            tile[r][cc] = Fn[(size_t)(p0 + r) * 256 + c0 + cc];
        }
        __syncthreads();
#pragma unroll
        for (int k = 0; k < 2; ++k) {
            int u = k * 256 + t;
            int cc = u & 63, S = u >> 6;          // S in [0,8)
            int G = S ^ (cc & 7);
            u16 v[8];
#pragma unroll
            for (int j = 0; j < 8; ++j) v[j] = f2bf(tile[G * 8 + j][cc]);
            uint4 pk;
            pk.x = (u32)v[0] | ((u32)v[1] << 16);
            pk.y = (u32)v[2] | ((u32)v[3] << 16);
            pk.z = (u32)v[4] | ((u32)v[5] << 16);
            pk.w = (u32)v[6] | ((u32)v[7] << 16);
            *(uint4*)&Gn[(c0 + cc) * 64 + S * 8] = pk;
        }
    }
}

// ---------- K4: out tile 64q x 256ch, p-step 64 ----------
// v4: NO Gt LDS staging at all. Gt fragments double-buffered in REGISTERS
// (bbA/bbB, 8 x bf16x8 each), prefetched one full step ahead (T14). PV is
// pure register MFMA except the af reads from sP. LDS = sP dbuf only (16KB).
// One raw s_barrier per step (lgkmcnt(0) only; bb loads stay in flight).
// na (next S-phase Q rows) issued BEFORE bb so S waits vmcnt(8), not 0.
// Manual 2x unroll keeps all buffer indices compile-time (rule #20).
__global__ __launch_bounds__(256, 2) void k4_attn(
    const u16* __restrict__ Q, const u16* __restrict__ Gt,
    const float* __restrict__ lgl, const float* __restrict__ mask,
    const float* __restrict__ ref, float* __restrict__ out) {
    const int t = threadIdx.x;
    const int w = t >> 6, L = t & 63, lane16 = L & 15, quad = L >> 4, l7 = lane16 & 7;
    const int bx = blockIdx.x;
    const int n = bx & 7, qb = bx >> 3;   // batch-per-XCD swizzle
    const int q0 = qb << 6;

    __shared__ u16 sP[2][4096];    // 16 KB: P' 64q x 64p (swizzled), dbuf

    const u16* Qn = Q + (size_t)n * 4096 * 64;
    const u16* Gtn = Gt + (size_t)n * 64 * 16384;
    const float* iln = lgl + n * 4096;

    // invariant B-frags: this block's 64 q-rows of Q
    f16x8 bq[4][2];
#pragma unroll
    for (int qt = 0; qt < 4; ++qt) {
        const int row = q0 + qt * 16 + lane16;
        bq[qt][0] = ldg8h(Qn + row * 64 + ((quad * 8) ^ (l7 * 8)));
        bq[qt][1] = ldg8h(Qn + row * 64 + ((32 + quad * 8) ^ (l7 * 8)));
    }

    // loop-invariant offsets
    const int sAg0 = (w * 16 + lane16) * 64 + ((quad * 8) ^ (l7 * 8));
    const int sAg1 = (w * 16 + lane16) * 64 + ((32 + quad * 8) ^ (l7 * 8));
    int wrP[4];
#pragma unroll
    for (int qt = 0; qt < 4; ++qt)
        wrP[qt] = (qt * 16 + lane16) * 64 +
                  ((w * 16 + 8 * (quad >> 1)) ^ (l7 * 8)) + 4 * (quad & 1);
    int rdP[4][2], sOf[4][2];
#pragma unroll
    for (int m = 0; m < 4; ++m)
#pragma unroll
        for (int h = 0; h < 2; ++h)
            rdP[m][h] = (m * 16 + lane16) * 64 + ((h * 32 + quad * 8) ^ (l7 * 8));
#pragma unroll
    for (int nt = 0; nt < 4; ++nt)
#pragma unroll
        for (int h = 0; h < 2; ++h)
            sOf[nt][h] = (w * 64 + nt * 16 + lane16) * 64 + ((h * 32 + quad * 8) ^ (l7 * 8));

    const f32x4 z4 = {0.f, 0.f, 0.f, 0.f};
    f32x4 acc[4][4];
#pragma unroll
    for (int a = 0; a < 4; ++a)
#pragma unroll
        for (int b = 0; b < 4; ++b) acc[a][b] = z4;

    f16x8 na0, na1;
    float4 nil4;
    bf16x8 bbA[8], bbB[8];

    // S-phase: compute P' tile for one step from register operands -> sP buf
    auto s_phase = [&](f16x8 a0, f16x8 a1, float4 il4, u16* dst) {
        float lg0 = il4.x, lg1 = il4.y, lg2 = il4.z, lg3 = il4.w;
#pragma unroll
        for (int qt = 0; qt < 4; ++qt) {
            f32x4 z = z4;
            z = mfma_h(a0, bq[qt][0], z);
            z = mfma_h(a1, bq[qt][1], z);
            uint2 pk;
            pk.x = pkbf2(__builtin_exp2f(__builtin_fmaf(z[0], LOG2E, lg0)),
                         __builtin_exp2f(__builtin_fmaf(z[1], LOG2E, lg1)));
            pk.y = pkbf2(__builtin_exp2f(__builtin_fmaf(z[2], LOG2E, lg2)),
                         __builtin_exp2f(__builtin_fmaf(z[3], LOG2E, lg3)));
            *(uint2*)&dst[wrP[qt]] = pk;
        }
    };
    // issue next-step Gt fragment loads into a register bank
    auto load_bb = [&](const u16* gstep, bf16x8* bb) {
#pragma unroll
        for (int h = 0; h < 2; ++h)
#pragma unroll
            for (int nt = 0; nt < 4; ++nt)
                bb[h * 4 + nt] = ldg8b(gstep + sOf[nt][h]);
    };
    // PV: af from sP (LDS), bb from registers
    auto pv_phase = [&](const u16* sPc, const bf16x8* bb) {
        __builtin_amdgcn_s_setprio(1);
#pragma unroll
        for (int h = 0; h < 2; ++h) {
            bf16x8 af[4];
#pragma unroll
            for (int m = 0; m < 4; ++m) af[m] = ldg8b(&sPc[rdP[m][h]]);
#pragma unroll
            for (int nt = 0; nt < 4; ++nt)
#pragma unroll
                for (int m = 0; m < 4; ++m)
                    acc[m][nt] = mfma_bf(af[m], bb[h * 4 + nt], acc[m][nt]);
        }
        __builtin_amdgcn_s_setprio(0);
    };

    // ---- prologue ----
    // S(0) -> sP[0] (direct loads, consumed immediately)
    {
        f16x8 a0 = ldg8h(Qn + sAg0);
        f16x8 a1 = ldg8h(Qn + sAg1);
        float4 il4 = *(const float4*)(iln + w * 16 + quad * 4);
        s_phase(a0, a1, il4, &sP[0][0]);
    }
    __builtin_amdgcn_sched_barrier(0);
    // na(1) first (so S(1) waits vmcnt(8), leaving bbA in flight) ...
    na0 = ldg8h(Qn + 4096 + sAg0);
    na1 = ldg8h(Qn + 4096 + sAg1);
    nil4 = *(const float4*)(iln + 64 + w * 16 + quad * 4);
    __builtin_amdgcn_sched_barrier(0);
    // ... then bbA <- Gt(0)
    load_bb(Gtn, bbA);
    __builtin_amdgcn_sched_barrier(0);
    asm volatile("s_waitcnt lgkmcnt(0)" ::: "memory");
    __builtin_amdgcn_s_barrier();

#pragma unroll 1
    for (int j = 0; j < 32; ++j) {
        const int i = 2 * j;
        // ================= even body: step i (sP[0], bbA) =================
        // S(i+1) -> sP[1]   (i+1 <= 63 always)
        s_phase(na0, na1, nil4, &sP[1][0]);
        __builtin_amdgcn_sched_barrier(0);
        if (i + 2 < 64) {
            na0 = ldg8h(Qn + (size_t)(i + 2) * 4096 + sAg0);
            na1 = ldg8h(Qn + (size_t)(i + 2) * 4096 + sAg1);
            nil4 = *(const float4*)(iln + (i + 2) * 64 + w * 16 + quad * 4);
        }
        __builtin_amdgcn_sched_barrier(0);
        load_bb(Gtn + (size_t)(i + 1) * 16384, bbB);   // i+1 <= 63 always
        __builtin_amdgcn_sched_barrier(0);
        pv_phase(&sP[0][0], bbA);
        asm volatile("s_waitcnt lgkmcnt(0)" ::: "memory");
        __builtin_amdgcn_s_barrier();

        // ================= odd body: step i+1 (sP[1], bbB) ================
        if (i + 2 < 64) {
            // S(i+2) -> sP[0]
            s_phase(na0, na1, nil4, &sP[0][0]);
            __builtin_amdgcn_sched_barrier(0);
            if (i + 3 < 64) {
                na0 = ldg8h(Qn + (size_t)(i + 3) * 4096 + sAg0);
                na1 = ldg8h(Qn + (size_t)(i + 3) * 4096 + sAg1);
                nil4 = *(const float4*)(iln + (i + 3) * 64 + w * 16 + quad * 4);
            }
            __builtin_amdgcn_sched_barrier(0);
            load_bb(Gtn + (size_t)(i + 2) * 16384, bbA);
            __builtin_amdgcn_sched_barrier(0);
        }
        pv_phase(&sP[1][0], bbB);
        asm volatile("s_waitcnt lgkmcnt(0)" ::: "memory");
        __builtin_amdgcn_s_barrier();
    }

    // ---- epilogue: replicate the reference's reshape scramble ----
    // out pixel = ch*16 + (qb>>2), out channel = (qb&3)*64 + q_local
    const int tb = qb >> 2;
    const int cb = (qb & 3) * 64;
    const float* maskn = mask + n * 4096;
    const float* refn = ref + (size_t)n * 4096 * 256;
    float* outn = out + (size_t)n * 4096 * 512;
#pragma unroll
    for (int nt = 0; nt < 4; ++nt) {
        const int ch = w * 64 + nt * 16 + lane16;
        const int pixel = ch * 16 + tb;
        const float m = maskn[pixel];
#pragma unroll
        for (int mt = 0; mt < 4; ++mt) {
            const int c4 = cb + mt * 16 + quad * 4;
            float4 r4 = *(const float4*)(refn + (size_t)pixel * 256 + c4);
            float a0 = acc[mt][nt][0], a1 = acc[mt][nt][1];
            float a2 = acc[mt][nt][2], a3 = acc[mt][nt][3];
            float4 a4 = {a0, a1, a2, a3};
            float4 bl4 = {m * a0 + (1.f - m) * r4.x,
                          m * a1 + (1.f - m) * r4.y,
                          m * a2 + (1.f - m) * r4.z,
                          m * a3 + (1.f - m) * r4.w};
            *(float4*)(outn + (size_t)pixel * 512 + 256 + c4) = a4;   // src_att
            *(float4*)(outn + (size_t)pixel * 512 + c4) = bl4;        // ex_guide_flow
        }
    }
}

extern "C" void kernel_launch(void* const* d_in, const int* in_sizes, int n_in,
                              void* d_out, int out_size, void* d_ws, size_t ws_size,
                              hipStream_t stream) {
    const float* mask = (const float*)d_in[0];   // (8,64,64) f32
    const float* F    = (const float*)d_in[1];   // (8,64,64,256) f32
    const float* ref  = (const float*)d_in[2];   // (8,64,64,256) f32
    const float* Wq   = (const float*)d_in[3];   // (256,64) f32
    float* out = (float*)d_out;                  // (8,64,64,512) f32
    char* ws = (char*)d_ws;

    u16*   Wthi = (u16*)ws;                                     // 32 KB
    u16*   Wtlo = (u16*)(ws + 32768);                           // 32 KB
    u16*   Qh   = (u16*)(ws + 65536);                           // 4 MB (fp16, swizzled)
    float* lgl  = (float*)(ws + 65536 + 4194304);               // 128 KB (-log2 of denom)
    u16*   Gt   = (u16*)(ws + 65536 + 4194304 + 131072);        // 16 MB (bf16, swizzled)

    k0_wt    <<<64,   256, 0, stream>>>(Wq, Wthi, Wtlo);
    k1_query <<<512,  256, 0, stream>>>(F, Wthi, Wtlo, Qh);
    k2_suminv<<<1024, 256, 0, stream>>>(Qh, lgl);
    k3_gt    <<<512,  256, 0, stream>>>(F, Gt);
    k4_attn  <<<512,  256, 0, stream>>>(Qh, Gt, lgl, mask, ref, out);
}